// Round 12
// baseline (33.743 us; speedup 1.0000x reference)
//
#include <hip/hip_runtime.h>
#include <hip/hip_fp16.h>

// AdaCoF sampler: out[b,c,h,w] = sum_k weights[b,k,h,w] * bilinear(image[b,c], y+dy, x+dx)
// B=4, C=3, H=W=256, K2=49.
// R11 post-mortem: 2-ahead prefetch flat -> not stream-latency bound.
// Occupancy stuck ~34% despite nominal 32 waves/CU; per-wave phases can't
// overlap with ~2.7 waves/SIMD effective.
// R12: halve block granularity for real TLP: tile 64x2 px, 256-thr blocks
// (2 k-halves x 128 px), 2048 blocks -> 8 blocks/CU, finer barrier scope,
// smaller tail quantum. Staging/px rises 1.8x (halo 19x81 per 128 px) --
// accepted cost. Memory structure (fp16 8B cells, 2x ds_read2_b64/tap,
// 1-ahead prefetch, badm backstop) = R10 verbatim.

#define BB 4
#define CC 3
#define HH 256
#define WW 256
#define K2 49
#define HWSZ (HH * WW)
#define SCALE (256.0f / 255.0f)

#define ROWS 19          // halo rows: [Y0-8, Y0+10]  (py_rel in [0.47,16.6])
#define COLS 81          // halo cols: [X0-8, X0+72]  (px_rel in [0.47,78.6])
#define NCELL (ROWS * COLS)   // 1539

struct alignas(8) Cell { __half2 a, b; };   // a = {ch0,ch1}, b = {ch2, 0}

__global__ void __launch_bounds__(256)
adacof_tile(const float* __restrict__ img,
            const float* __restrict__ offsets,
            const float* __restrict__ weights,
            float* __restrict__ out) {
    __shared__ Cell tp[NCELL];           // 12,312 B
    __shared__ float redbuf[CC][128];    //  1,536 B

    const int t = threadIdx.x;
    const int h = t >> 7;                // k-half (wave-uniform: lanes 0-127 vs 128-255)
    const int pix = t & 127;
    const int tx = pix & 63;
    const int ty = pix >> 6;             // 0..1

    const int bid = blockIdx.x;
    const int b = bid >> 9;
    const int tIdx = bid & 511;
    const int X0 = (tIdx & 3) << 6;      // 4 tile cols of 64
    const int Y0 = (tIdx >> 2) << 1;     // 128 tile rows of 2
    const int OX = X0 - 8, OY = Y0 - 8;

    const float* imgB = img + (size_t)b * (CC * HWSZ);

    // ---- stage halo: clamped-replicated borders, fp16-packed ----
    {
        const float* p0 = imgB;
        const float* p1 = imgB + HWSZ;
        const float* p2 = imgB + 2 * HWSZ;
        for (int i = t; i < NCELL; i += 256) {
            int ry = i / COLS;
            int rx = i - ry * COLS;
            int gy = min(max(OY + ry, 0), HH - 1);
            int gx = min(max(OX + rx, 0), WW - 1);
            int gi = gy * WW + gx;
            Cell cell;
            cell.a = __floats2half2_rn(p0[gi], p1[gi]);
            cell.b = __floats2half2_rn(p2[gi], 0.0f);
            tp[i] = cell;
        }
    }
    __syncthreads();

    const int hw = (Y0 + ty) * WW + X0 + tx;
    const int kbase = h * 24;            // half0: k 0..23 ; half1: k 24..47 + 48
    const float* offH = offsets + (size_t)b * (2 * K2 * HWSZ)
                                + (size_t)(2 * kbase) * HWSZ + hw;
    const float* wgtH = weights + (size_t)b * (K2 * HWSZ)
                                + (size_t)kbase * HWSZ + hw;

    // tile-frame sampling constants. Border replication == reference clamp
    // whenever |dx|,|dy| <= 7.
    const float Axt = (float)(X0 + tx) * SCALE - 0.5f - (float)OX;
    const float Ayt = (float)(Y0 + ty) * SCALE - 0.5f - (float)OY;

    float acc0 = 0.0f, acc1 = 0.0f, acc2 = 0.0f;
    float badv = 0.0f;
    __half2 acc01h = __floats2half2_rn(0.0f, 0.0f);
    __half2 acc2h = acc01h;

    auto TAP = [&](float dx, float dy, float wg) {
        badv = fmaxf(fmaxf(fabsf(dx), fabsf(dy)), badv);   // v_max3 w/ abs mods
        float px = fmaf(dx, SCALE, Axt);
        float py = fmaf(dy, SCALE, Ayt);
        px = __builtin_amdgcn_fmed3f(px, 0.0f, 79.0f);     // halo clamp, 1 instr
        py = __builtin_amdgcn_fmed3f(py, 0.0f, 17.0f);
        float x0f = floorf(px), y0f = floorf(py);
        float wx = px - x0f, wy = py - y0f;
        int i00 = (int)fmaf(y0f, (float)COLS, x0f);
        float a11 = wx * wy;
        float a10 = wy - a11;
        float a01 = wx - a11;
        float a00 = (1.0f - wx) - a10;
        a00 *= wg; a01 *= wg; a10 *= wg; a11 *= wg;
        __half2 W00 = __floats2half2_rn(a00, a00);
        __half2 W01 = __floats2half2_rn(a01, a01);
        __half2 W10 = __floats2half2_rn(a10, a10);
        __half2 W11 = __floats2half2_rn(a11, a11);
        Cell q00 = tp[i00];
        Cell q01 = tp[i00 + 1];
        Cell q10 = tp[i00 + COLS];
        Cell q11 = tp[i00 + COLS + 1];
        acc01h = __hfma2(q00.a, W00, acc01h);
        acc2h  = __hfma2(q00.b, W00, acc2h);
        acc01h = __hfma2(q01.a, W01, acc01h);
        acc2h  = __hfma2(q01.b, W01, acc2h);
        acc01h = __hfma2(q10.a, W10, acc01h);
        acc2h  = __hfma2(q10.b, W10, acc2h);
        acc01h = __hfma2(q11.a, W11, acc01h);
        acc2h  = __hfma2(q11.b, W11, acc2h);
    };

    auto FLUSH = [&]() {
        float2 f01 = __half22float2(acc01h);
        float2 f2 = __half22float2(acc2h);
        acc0 += f01.x;
        acc1 += f01.y;
        acc2 += f2.x;
        acc01h = __floats2half2_rn(0.0f, 0.0f);
        acc2h = acc01h;
    };

    // ---- stream pipeline: 6 groups of 4 taps, prefetch one group ahead ----
    float dxv[2][4], dyv[2][4], wgv[2][4];
    #pragma unroll
    for (int j = 0; j < 4; ++j) {
        dxv[0][j] = offH[(size_t)(2 * j) * HWSZ];
        dyv[0][j] = offH[(size_t)(2 * j + 1) * HWSZ];
        wgv[0][j] = wgtH[(size_t)j * HWSZ];
    }
    float dxt = 0.0f, dyt = 0.0f, wgt = 0.0f;
    if (h == 1) {   // tail tap k=48 (rel planes 48,49; rel weight 24)
        dxt = offH[(size_t)48 * HWSZ];
        dyt = offH[(size_t)49 * HWSZ];
        wgt = wgtH[(size_t)24 * HWSZ];
    }
    __builtin_amdgcn_sched_barrier(0);

    #pragma unroll
    for (int g = 0; g < 6; ++g) {
        if (g < 5) {
            #pragma unroll
            for (int j = 0; j < 4; ++j) {
                int k = 4 * (g + 1) + j;
                dxv[(g + 1) & 1][j] = offH[(size_t)(2 * k) * HWSZ];
                dyv[(g + 1) & 1][j] = offH[(size_t)(2 * k + 1) * HWSZ];
                wgv[(g + 1) & 1][j] = wgtH[(size_t)k * HWSZ];
            }
        }
        __builtin_amdgcn_sched_barrier(0);   // loads issue before this group's compute
        #pragma unroll
        for (int j = 0; j < 4; ++j)
            TAP(dxv[g & 1][j], dyv[g & 1][j], wgv[g & 1][j]);
        FLUSH();                             // bound fp16 accumulation error
    }
    if (h == 1) {
        TAP(dxt, dyt, wgt);
        FLUSH();
    }

    // ---- cold correctness backstop (offsets ~N(0,1): never taken) ----
    if (__any(badv > 7.0f)) {
        if (badv > 7.0f) {
            const float Axi = (float)(X0 + tx) * SCALE - 0.5f;
            const float Ayi = (float)(Y0 + ty) * SCALE - 0.5f;
            float a0 = 0.0f, a1 = 0.0f, a2 = 0.0f;
            int ntap = (h == 1) ? 25 : 24;
            for (int idx = 0; idx < ntap; ++idx) {
                int k = (idx == 24) ? 48 : (kbase + idx);
                float dx = offsets[(size_t)b * (2 * K2 * HWSZ) + (size_t)(2 * k) * HWSZ + hw];
                float dy = offsets[(size_t)b * (2 * K2 * HWSZ) + (size_t)(2 * k + 1) * HWSZ + hw];
                float wg = weights[(size_t)b * (K2 * HWSZ) + (size_t)k * HWSZ + hw];
                float px = fminf(fmaxf(fmaf(dx, SCALE, Axi), 0.0f), 255.0f);
                float py = fminf(fmaxf(fmaf(dy, SCALE, Ayi), 0.0f), 255.0f);
                float x0f = floorf(px), y0f = floorf(py);
                float wx = px - x0f, wy = py - y0f;
                int ix0 = (int)x0f, iy0 = (int)y0f;
                int ix1 = min(ix0 + 1, WW - 1), iy1 = min(iy0 + 1, HH - 1);
                float w11 = wx * wy, w10 = wy - w11, w01 = wx - w11;
                float w00 = (1.0f - wx) - w10;
                #pragma unroll
                for (int c = 0; c < CC; ++c) {
                    const float* p = imgB + (size_t)c * HWSZ;
                    float bil = p[iy0 * WW + ix0] * w00 + p[iy0 * WW + ix1] * w01
                              + p[iy1 * WW + ix0] * w10 + p[iy1 * WW + ix1] * w11;
                    if (c == 0) a0 = fmaf(wg, bil, a0);
                    else if (c == 1) a1 = fmaf(wg, bil, a1);
                    else a2 = fmaf(wg, bil, a2);
                }
            }
            acc0 = a0; acc1 = a1; acc2 = a2;
        }
    }

    // ---- combine halves, write out ----
    if (h == 1) {
        redbuf[0][pix] = acc0;
        redbuf[1][pix] = acc1;
        redbuf[2][pix] = acc2;
    }
    __syncthreads();
    if (h == 0) {
        acc0 += redbuf[0][pix];
        acc1 += redbuf[1][pix];
        acc2 += redbuf[2][pix];
        float* o = out + (size_t)b * (CC * HWSZ) + hw;
        o[0] = acc0;
        o[HWSZ] = acc1;
        o[2 * HWSZ] = acc2;
    }
}

extern "C" void kernel_launch(void* const* d_in, const int* in_sizes, int n_in,
                              void* d_out, int out_size, void* d_ws, size_t ws_size,
                              hipStream_t stream) {
    const float* image = (const float*)d_in[0];
    const float* offsets = (const float*)d_in[1];
    const float* weights = (const float*)d_in[2];
    float* out = (float*)d_out;

    // 4 batches x 512 tiles (64x2 px); 256 threads = 128 px x 2 k-halves
    adacof_tile<<<BB * 512, 256, 0, stream>>>(image, offsets, weights, out);
}

// Round 13
// 32.326 us; speedup vs baseline: 1.0438x; 1.0438x over previous
//
#include <hip/hip_runtime.h>
#include <hip/hip_fp16.h>

// AdaCoF sampler: out[b,c,h,w] = sum_k weights[b,k,h,w] * bilinear(image[b,c], y+dy, x+dx)
// B=4, C=3, H=W=256, K2=49.
// FINAL (R13 = R10 revert, best measured: 32.5us bench).
// Journey: 79us naive -> 68us k-split TLP -> 39.5us LDS-gather tile ->
// 35.8us wide ds_read2 -> 33.5us bf16 cells -> 32.5us fp16 pk-math (R10).
// R11 (2-ahead prefetch), R12 (finer blocks) both flat -> structure is
// overlap-saturated: 160MB streamed at ~4.9TB/s effective (~78% of the
// 6.3TB/s copy ceiling) while hiding 12.8M random bilinear LDS gathers,
// ~23% VALU, and 4.6e6 conflict cycles beneath the stream.
// Structure:
//  - 64x4 px tile per 512-thr block; wave = one 64-px row -> stream loads
//    perfectly coalesced (256B/instr); 2 k-halves across block halves,
//    LDS-reduced at the end.
//  - image halo 21x81 staged in LDS as fp16 {ch0,ch1|ch2,0} 8B cells;
//    each bilinear tap = 2x ds_read2_b64 (4 corners, 3 channels) on the
//    LDS pipe -- divergent gathers off the VMEM path (the R5->R6 2x win).
//  - per-tap math: v_med3 clamps, folded corner weights, 8x v_pk_fma_f16,
//    f32 flush per 4-tap group (absmax 0.25 << 0.94 threshold).
//  - streams: 6 groups of 4 taps, 1-group-ahead double-buffer prefetch,
//    sched_barrier(0) fencing (keeps loads batched; R2's sink bug).
//  - correctness for ANY offset magnitude: per-tap |dx|,|dy|>7 flag ->
//    cold full-f32 global-memory recompute of the whole pixel.

#define BB 4
#define CC 3
#define HH 256
#define WW 256
#define K2 49
#define HWSZ (HH * WW)
#define SCALE (256.0f / 255.0f)

#define ROWS 21          // halo rows: [Y0-8, Y0+12]
#define COLS 81          // halo cols: [X0-8, X0+72]
#define NCELL (ROWS * COLS)   // 1701

struct alignas(8) Cell { __half2 a, b; };   // a = {ch0,ch1}, b = {ch2, 0}

__global__ void __launch_bounds__(512)
adacof_tile(const float* __restrict__ img,
            const float* __restrict__ offsets,
            const float* __restrict__ weights,
            float* __restrict__ out) {
    __shared__ Cell tp[NCELL];           // 13,608 B
    __shared__ float redbuf[CC][256];    //  3,072 B

    const int t = threadIdx.x;
    const int h = t >> 8;                // k-half (wave-uniform)
    const int pix = t & 255;
    const int tx = pix & 63;
    const int ty = pix >> 6;             // wave = one 64-px row

    const int bid = blockIdx.x;
    const int b = bid >> 8;
    const int tIdx = bid & 255;
    const int X0 = (tIdx & 3) << 6;      // 4 tile cols of 64
    const int Y0 = (tIdx >> 2) << 2;     // 64 tile rows of 4
    const int OX = X0 - 8, OY = Y0 - 8;

    const float* imgB = img + (size_t)b * (CC * HWSZ);

    // ---- stage halo: clamped-replicated borders, fp16-packed ----
    {
        const float* p0 = imgB;
        const float* p1 = imgB + HWSZ;
        const float* p2 = imgB + 2 * HWSZ;
        for (int i = t; i < NCELL; i += 512) {
            int ry = i / COLS;
            int rx = i - ry * COLS;
            int gy = min(max(OY + ry, 0), HH - 1);
            int gx = min(max(OX + rx, 0), WW - 1);
            int gi = gy * WW + gx;
            Cell cell;
            cell.a = __floats2half2_rn(p0[gi], p1[gi]);
            cell.b = __floats2half2_rn(p2[gi], 0.0f);
            tp[i] = cell;
        }
    }
    __syncthreads();

    const int hw = (Y0 + ty) * WW + X0 + tx;
    const int kbase = h * 24;            // half0: k 0..23 ; half1: k 24..47 + 48
    const float* offH = offsets + (size_t)b * (2 * K2 * HWSZ)
                                + (size_t)(2 * kbase) * HWSZ + hw;
    const float* wgtH = weights + (size_t)b * (K2 * HWSZ)
                                + (size_t)kbase * HWSZ + hw;

    // tile-frame sampling constants. Border replication == reference clamp
    // whenever |dx|,|dy| <= 7.
    const float Axt = (float)(X0 + tx) * SCALE - 0.5f - (float)OX;
    const float Ayt = (float)(Y0 + ty) * SCALE - 0.5f - (float)OY;

    float acc0 = 0.0f, acc1 = 0.0f, acc2 = 0.0f;
    float badv = 0.0f;
    __half2 acc01h = __floats2half2_rn(0.0f, 0.0f);
    __half2 acc2h = acc01h;

    auto TAP = [&](float dx, float dy, float wg) {
        badv = fmaxf(fmaxf(fabsf(dx), fabsf(dy)), badv);   // v_max3 w/ abs mods
        float px = fmaf(dx, SCALE, Axt);
        float py = fmaf(dy, SCALE, Ayt);
        px = __builtin_amdgcn_fmed3f(px, 0.0f, 79.0f);     // halo clamp, 1 instr
        py = __builtin_amdgcn_fmed3f(py, 0.0f, 19.0f);
        float x0f = floorf(px), y0f = floorf(py);
        float wx = px - x0f, wy = py - y0f;
        int i00 = (int)fmaf(y0f, (float)COLS, x0f);
        float a11 = wx * wy;
        float a10 = wy - a11;
        float a01 = wx - a11;
        float a00 = (1.0f - wx) - a10;
        a00 *= wg; a01 *= wg; a10 *= wg; a11 *= wg;
        __half2 W00 = __floats2half2_rn(a00, a00);
        __half2 W01 = __floats2half2_rn(a01, a01);
        __half2 W10 = __floats2half2_rn(a10, a10);
        __half2 W11 = __floats2half2_rn(a11, a11);
        Cell q00 = tp[i00];
        Cell q01 = tp[i00 + 1];
        Cell q10 = tp[i00 + COLS];
        Cell q11 = tp[i00 + COLS + 1];
        acc01h = __hfma2(q00.a, W00, acc01h);
        acc2h  = __hfma2(q00.b, W00, acc2h);
        acc01h = __hfma2(q01.a, W01, acc01h);
        acc2h  = __hfma2(q01.b, W01, acc2h);
        acc01h = __hfma2(q10.a, W10, acc01h);
        acc2h  = __hfma2(q10.b, W10, acc2h);
        acc01h = __hfma2(q11.a, W11, acc01h);
        acc2h  = __hfma2(q11.b, W11, acc2h);
    };

    auto FLUSH = [&]() {
        float2 f01 = __half22float2(acc01h);
        float2 f2 = __half22float2(acc2h);
        acc0 += f01.x;
        acc1 += f01.y;
        acc2 += f2.x;
        acc01h = __floats2half2_rn(0.0f, 0.0f);
        acc2h = acc01h;
    };

    // ---- stream pipeline: 6 groups of 4 taps, prefetch one group ahead ----
    float dxv[2][4], dyv[2][4], wgv[2][4];
    #pragma unroll
    for (int j = 0; j < 4; ++j) {
        dxv[0][j] = offH[(size_t)(2 * j) * HWSZ];
        dyv[0][j] = offH[(size_t)(2 * j + 1) * HWSZ];
        wgv[0][j] = wgtH[(size_t)j * HWSZ];
    }
    float dxt = 0.0f, dyt = 0.0f, wgt = 0.0f;
    if (h == 1) {   // tail tap k=48 (rel planes 48,49; rel weight 24)
        dxt = offH[(size_t)48 * HWSZ];
        dyt = offH[(size_t)49 * HWSZ];
        wgt = wgtH[(size_t)24 * HWSZ];
    }
    __builtin_amdgcn_sched_barrier(0);

    #pragma unroll
    for (int g = 0; g < 6; ++g) {
        if (g < 5) {
            #pragma unroll
            for (int j = 0; j < 4; ++j) {
                int k = 4 * (g + 1) + j;
                dxv[(g + 1) & 1][j] = offH[(size_t)(2 * k) * HWSZ];
                dyv[(g + 1) & 1][j] = offH[(size_t)(2 * k + 1) * HWSZ];
                wgv[(g + 1) & 1][j] = wgtH[(size_t)k * HWSZ];
            }
        }
        __builtin_amdgcn_sched_barrier(0);   // loads issue before this group's compute
        #pragma unroll
        for (int j = 0; j < 4; ++j)
            TAP(dxv[g & 1][j], dyv[g & 1][j], wgv[g & 1][j]);
        FLUSH();                             // bound fp16 accumulation error
    }
    if (h == 1) {
        TAP(dxt, dyt, wgt);
        FLUSH();
    }

    // ---- cold correctness backstop (offsets ~N(0,1): never taken) ----
    if (__any(badv > 7.0f)) {
        if (badv > 7.0f) {
            const float Axi = (float)(X0 + tx) * SCALE - 0.5f;
            const float Ayi = (float)(Y0 + ty) * SCALE - 0.5f;
            float a0 = 0.0f, a1 = 0.0f, a2 = 0.0f;
            int ntap = (h == 1) ? 25 : 24;
            for (int idx = 0; idx < ntap; ++idx) {
                int k = (idx == 24) ? 48 : (kbase + idx);
                float dx = offsets[(size_t)b * (2 * K2 * HWSZ) + (size_t)(2 * k) * HWSZ + hw];
                float dy = offsets[(size_t)b * (2 * K2 * HWSZ) + (size_t)(2 * k + 1) * HWSZ + hw];
                float wg = weights[(size_t)b * (K2 * HWSZ) + (size_t)k * HWSZ + hw];
                float px = fminf(fmaxf(fmaf(dx, SCALE, Axi), 0.0f), 255.0f);
                float py = fminf(fmaxf(fmaf(dy, SCALE, Ayi), 0.0f), 255.0f);
                float x0f = floorf(px), y0f = floorf(py);
                float wx = px - x0f, wy = py - y0f;
                int ix0 = (int)x0f, iy0 = (int)y0f;
                int ix1 = min(ix0 + 1, WW - 1), iy1 = min(iy0 + 1, HH - 1);
                float w11 = wx * wy, w10 = wy - w11, w01 = wx - w11;
                float w00 = (1.0f - wx) - w10;
                #pragma unroll
                for (int c = 0; c < CC; ++c) {
                    const float* p = imgB + (size_t)c * HWSZ;
                    float bil = p[iy0 * WW + ix0] * w00 + p[iy0 * WW + ix1] * w01
                              + p[iy1 * WW + ix0] * w10 + p[iy1 * WW + ix1] * w11;
                    if (c == 0) a0 = fmaf(wg, bil, a0);
                    else if (c == 1) a1 = fmaf(wg, bil, a1);
                    else a2 = fmaf(wg, bil, a2);
                }
            }
            acc0 = a0; acc1 = a1; acc2 = a2;
        }
    }

    // ---- combine halves, write out ----
    if (h == 1) {
        redbuf[0][pix] = acc0;
        redbuf[1][pix] = acc1;
        redbuf[2][pix] = acc2;
    }
    __syncthreads();
    if (h == 0) {
        acc0 += redbuf[0][pix];
        acc1 += redbuf[1][pix];
        acc2 += redbuf[2][pix];
        float* o = out + (size_t)b * (CC * HWSZ) + hw;
        o[0] = acc0;
        o[HWSZ] = acc1;
        o[2 * HWSZ] = acc2;
    }
}

extern "C" void kernel_launch(void* const* d_in, const int* in_sizes, int n_in,
                              void* d_out, int out_size, void* d_ws, size_t ws_size,
                              hipStream_t stream) {
    const float* image = (const float*)d_in[0];
    const float* offsets = (const float*)d_in[1];
    const float* weights = (const float*)d_in[2];
    float* out = (float*)d_out;

    // 4 batches x 256 tiles (64x4 px); 512 threads = 256 px x 2 k-halves
    adacof_tile<<<BB * 256, 512, 0, stream>>>(image, offsets, weights, out);
}